// Round 10
// baseline (370.414 us; speedup 1.0000x reference)
//
#include <hip/hip_runtime.h>
#include <hip/hip_bf16.h>
#include <math.h>

#define NUM_GRAPHS 1024
#define SBLK 256          // sort blocks in fused CSR kernel
#define CAP 4096          // per-bucket ebuf capacity (mean 2046, 45 sigma)

typedef __attribute__((ext_vector_type(8))) short bf16x8;
typedef __attribute__((ext_vector_type(4))) float f32x4;

static __device__ __forceinline__ unsigned short f2bf(float f) {
    union { float f; unsigned u; } v; v.f = f;
    unsigned r = v.u + 0x7fffu + ((v.u >> 16) & 1u);   // round-to-nearest-even
    return (unsigned short)(r >> 16);
}
static __device__ __forceinline__ float bf_lo(unsigned u) { return __uint_as_float(u << 16); }
static __device__ __forceinline__ float bf_hi(unsigned u) { return __uint_as_float(u & 0xffff0000u); }

// XOR-chunk swizzle: (row, chunk of 8 elems) -> element index
__device__ __forceinline__ int swz_base(int row, int chunk) {
    return row * 128 + ((chunk ^ (row & 7)) << 3);
}

// exclusive scan of min(tot[i],CAP) into bb[0..nbuck]; 256 threads, nbuck<=1024
static __device__ void scan_tot(const int* __restrict__ tot, int nbuck,
                                int* bb, int* tmp) {
    const int t = threadIdx.x;
    int v[4];
    int lsum = 0;
    #pragma unroll
    for (int j = 0; j < 4; ++j) {
        int idx = 4 * t + j;
        v[j] = (idx < nbuck) ? min(tot[idx], CAP) : 0;
        lsum += v[j];
    }
    tmp[t] = lsum;
    __syncthreads();
    for (int off = 1; off < 256; off <<= 1) {
        int a = (t >= off) ? tmp[t - off] : 0;
        __syncthreads();
        tmp[t] += a;
        __syncthreads();
    }
    int run = tmp[t] - lsum;
    #pragma unroll
    for (int j = 0; j < 4; ++j) {
        int idx = 4 * t + j;
        if (idx < nbuck) bb[idx] = run;
        run += v[j];
    }
    if (t == 255) bb[nbuck] = tmp[255];
    __syncthreads();
}

// ---------------- fused CSR pass 1: hist + chunk-reserve + scatter ----------------
// Also: x->bf16 (row-major), zero G, weight prep — as extra block ranges.
__global__ void k_sort(const int* __restrict__ eiSrc, const int* __restrict__ eiDst,
                       int E, int epb, int nbuck,
                       int* __restrict__ gcur, unsigned* __restrict__ ebuf,
                       const float* __restrict__ x, int N, unsigned* __restrict__ xb,
                       float* __restrict__ G,
                       const float* __restrict__ W0, const float* __restrict__ W1,
                       const float* __restrict__ W2, const float* __restrict__ W3,
                       unsigned short* __restrict__ wt) {
    if ((int)blockIdx.x < SBLK) {
        __shared__ int hist[1024];
        __shared__ int cur[1024];
        const int t = threadIdx.x;
        for (int i = t; i < 1024; i += 256) hist[i] = 0;
        __syncthreads();
        const int e0 = blockIdx.x * epb;
        const int e1 = min(E, e0 + epb);
        for (int e = e0 + t; e < e1; e += 256) atomicAdd(&hist[eiDst[e] >> 7], 1);
        __syncthreads();
        for (int b = t; b < nbuck; b += 256) {
            int c = hist[b];
            cur[b] = b * CAP + (c > 0 ? atomicAdd(&gcur[b], c) : 0);
        }
        __syncthreads();
        for (int e = e0 + t; e < e1; e += 256) {
            int d = eiDst[e];
            int s = eiSrc[e];
            int b = d >> 7;
            int pos = atomicAdd(&cur[b], 1);
            if (pos < (b + 1) * CAP)   // overflow guard
                ebuf[pos] = (unsigned)s | ((unsigned)(d & 127) << 25);
        }
    } else if ((int)blockIdx.x < SBLK + 2048) {
        const int n4 = N * 32;
        int i = (blockIdx.x - SBLK) * 256 + threadIdx.x;
        const int stride = 2048 * 256;
        const float4* x4 = (const float4*)x;
        for (; i < n4; i += stride) {
            float4 v = x4[i];
            unsigned lo = (unsigned)f2bf(v.x) | ((unsigned)f2bf(v.y) << 16);
            unsigned hi = (unsigned)f2bf(v.z) | ((unsigned)f2bf(v.w) << 16);
            ((uint2*)xb)[i] = make_uint2(lo, hi);
        }
    } else if ((int)blockIdx.x < SBLK + 2048 + 64) {
        int i = (blockIdx.x - SBLK - 2048) * 256 + threadIdx.x;
        float4* G4 = (float4*)G;
        for (; i < NUM_GRAPHS * 32; i += 64 * 256)
            G4[i] = make_float4(0.f, 0.f, 0.f, 0.f);
    } else {
        int lb = blockIdx.x - SBLK - 2048 - 64;     // 0..255
        int b4 = lb >> 6;                           // 0..3
        const float* W = (b4 == 0) ? W0 : (b4 == 1) ? W1 : (b4 == 2) ? W2 : W3;
        int idx = (lb & 63) * 256 + threadIdx.x;    // 0..16383
        int k = idx >> 7, n = idx & 127;
        wt[b4 * 16384 + n * 128 + k] = f2bf(W[idx]);
    }
}

// ---------------- shared MLP core: lA (swizzled bf16 A-tile) -> acc = relu-chain ----------------
// Runs mm1 (A@Wa + ba, relu -> lA), restage lW=WbT, mm2 (T@Wb). acc returned raw (pre-bias).
__device__ __forceinline__ void mlp_core(unsigned short* lA, unsigned short* lW,
                                         const unsigned short* __restrict__ WaT,
                                         const float* __restrict__ ba,
                                         const unsigned short* __restrict__ WbT,
                                         f32x4 (&acc)[4][4],
                                         int tid, int lane, int wr, int wc) {
    // stage Wa^T
    {
        const uint4* Wsrc = (const uint4*)WaT;
        #pragma unroll
        for (int i = 0; i < 8; ++i) {
            int c = tid + 256 * i;
            int row = c >> 4, q = c & 15;
            *(uint4*)&lW[swz_base(row, q)] = Wsrc[c];
        }
    }
    __syncthreads();

    const int am = lane & 15;
    const int kq = (lane >> 4) * 8;

    #pragma unroll
    for (int i = 0; i < 4; ++i)
        #pragma unroll
        for (int j = 0; j < 4; ++j) acc[i][j] = (f32x4){0.f, 0.f, 0.f, 0.f};

    #pragma unroll
    for (int ks = 0; ks < 4; ++ks) {
        int k0 = ks * 32 + kq;
        bf16x8 af[4], bq[4];
        #pragma unroll
        for (int i = 0; i < 4; ++i)
            af[i] = *(const bf16x8*)&lA[swz_base(wr + i * 16 + am, k0 >> 3)];
        #pragma unroll
        for (int j = 0; j < 4; ++j)
            bq[j] = *(const bf16x8*)&lW[swz_base(wc + j * 16 + am, k0 >> 3)];
        #pragma unroll
        for (int i = 0; i < 4; ++i)
            #pragma unroll
            for (int j = 0; j < 4; ++j)
                acc[i][j] = __builtin_amdgcn_mfma_f32_16x16x32_bf16(af[i], bq[j], acc[i][j], 0, 0, 0);
    }
    __syncthreads();   // all lA/lW reads complete

    // T = relu(acc + ba) -> lA; restage lW = Wb^T
    #pragma unroll
    for (int j = 0; j < 4; ++j) {
        int col = wc + j * 16 + am;
        float bias = ba[col];
        #pragma unroll
        for (int i = 0; i < 4; ++i) {
            int rowb = wr + i * 16 + (lane >> 4) * 4;
            #pragma unroll
            for (int r = 0; r < 4; ++r) {
                float t = acc[i][j][r] + bias;
                t = t > 0.f ? t : 0.f;
                int row = rowb + r;
                lA[swz_base(row, col >> 3) + (col & 7)] = f2bf(t);
            }
        }
    }
    {
        const uint4* Wsrc = (const uint4*)WbT;
        #pragma unroll
        for (int i = 0; i < 8; ++i) {
            int c = tid + 256 * i;
            int row = c >> 4, q = c & 15;
            *(uint4*)&lW[swz_base(row, q)] = Wsrc[c];
        }
    }
    __syncthreads();

    #pragma unroll
    for (int i = 0; i < 4; ++i)
        #pragma unroll
        for (int j = 0; j < 4; ++j) acc[i][j] = (f32x4){0.f, 0.f, 0.f, 0.f};

    #pragma unroll
    for (int ks = 0; ks < 4; ++ks) {
        int k0 = ks * 32 + kq;
        bf16x8 af[4], bq[4];
        #pragma unroll
        for (int i = 0; i < 4; ++i)
            af[i] = *(const bf16x8*)&lA[swz_base(wr + i * 16 + am, k0 >> 3)];
        #pragma unroll
        for (int j = 0; j < 4; ++j)
            bq[j] = *(const bf16x8*)&lW[swz_base(wc + j * 16 + am, k0 >> 3)];
        #pragma unroll
        for (int i = 0; i < 4; ++i)
            #pragma unroll
            for (int j = 0; j < 4; ++j)
                acc[i][j] = __builtin_amdgcn_mfma_f32_16x16x32_bf16(af[i], bq[j], acc[i][j], 0, 0, 0);
    }
}

// quarter-wave gather of node row `n` (8 feats per lane at chunk ql) -> uint4
__device__ __forceinline__ uint4 gather_row(const uint4* __restrict__ H4, int n, int ql,
                                            const int* lrp, const int* lsrcs, int loc) {
    uint4 s0 = H4[(size_t)n * 16 + ql];
    float a[8];
    a[0] = bf_lo(s0.x); a[1] = bf_hi(s0.x);
    a[2] = bf_lo(s0.y); a[3] = bf_hi(s0.y);
    a[4] = bf_lo(s0.z); a[5] = bf_hi(s0.z);
    a[6] = bf_lo(s0.w); a[7] = bf_hi(s0.w);
    int j = lrp[loc], e = lrp[loc + 1];
    while (j + 4 <= e) {
        int i0 = lsrcs[j], i1 = lsrcs[j + 1], i2 = lsrcs[j + 2], i3 = lsrcs[j + 3];
        uint4 v0 = H4[(size_t)i0 * 16 + ql];
        uint4 v1 = H4[(size_t)i1 * 16 + ql];
        uint4 v2 = H4[(size_t)i2 * 16 + ql];
        uint4 v3 = H4[(size_t)i3 * 16 + ql];
        a[0] += bf_lo(v0.x) + bf_lo(v1.x) + bf_lo(v2.x) + bf_lo(v3.x);
        a[1] += bf_hi(v0.x) + bf_hi(v1.x) + bf_hi(v2.x) + bf_hi(v3.x);
        a[2] += bf_lo(v0.y) + bf_lo(v1.y) + bf_lo(v2.y) + bf_lo(v3.y);
        a[3] += bf_hi(v0.y) + bf_hi(v1.y) + bf_hi(v2.y) + bf_hi(v3.y);
        a[4] += bf_lo(v0.z) + bf_lo(v1.z) + bf_lo(v2.z) + bf_lo(v3.z);
        a[5] += bf_hi(v0.z) + bf_hi(v1.z) + bf_hi(v2.z) + bf_hi(v3.z);
        a[6] += bf_lo(v0.w) + bf_lo(v1.w) + bf_lo(v2.w) + bf_lo(v3.w);
        a[7] += bf_hi(v0.w) + bf_hi(v1.w) + bf_hi(v2.w) + bf_hi(v3.w);
        j += 4;
    }
    while (j < e) {
        uint4 v = H4[(size_t)lsrcs[j] * 16 + ql];
        a[0] += bf_lo(v.x); a[1] += bf_hi(v.x);
        a[2] += bf_lo(v.y); a[3] += bf_hi(v.y);
        a[4] += bf_lo(v.z); a[5] += bf_hi(v.z);
        a[6] += bf_lo(v.w); a[7] += bf_hi(v.w);
        ++j;
    }
    uint4 o;
    o.x = (unsigned)f2bf(a[0]) | ((unsigned)f2bf(a[1]) << 16);
    o.y = (unsigned)f2bf(a[2]) | ((unsigned)f2bf(a[3]) << 16);
    o.z = (unsigned)f2bf(a[4]) | ((unsigned)f2bf(a[5]) << 16);
    o.w = (unsigned)f2bf(a[6]) | ((unsigned)f2bf(a[7]) << 16);
    return o;
}

// ---------------- conv1: CSR fine-sort + gather + 2-layer MLP, one block per bucket ----------------
__global__ __launch_bounds__(256, 2)
void k_conv1(const unsigned* __restrict__ ebuf, const int* __restrict__ gcur,
             int nbuck, int N, int* __restrict__ rp, int* __restrict__ srcs,
             const uint4* __restrict__ X4,
             const unsigned short* __restrict__ WaT, const float* __restrict__ ba,
             const unsigned short* __restrict__ WbT, const float* __restrict__ bb,
             unsigned short* __restrict__ Y) {
    __shared__ unsigned short lA[128 * 128];                       // 32 KB
    __shared__ __align__(16) unsigned char uraw[32 * 1024];        // CSR scratch ∪ lW
    int* bbp   = (int*)(uraw);             // [1025]
    int* tmpp  = (int*)(uraw + 4352);      // [256]
    int* hp    = (int*)(uraw + 5376);      // [128]
    int* curp  = (int*)(uraw + 5888);      // [128]
    int* lrp   = (int*)(uraw + 6400);      // [129]
    int* lsrcs = (int*)(uraw + 6928);      // [CAP]
    unsigned short* lW = (unsigned short*)uraw;

    const int t = threadIdx.x;
    const int b = blockIdx.x;

    // ---- CSR fine sort (phase A) ----
    scan_tot(gcur, nbuck, bbp, tmpp);
    const int base = bbp[b];
    const int cntb = bbp[b + 1] - base;
    const unsigned* eb = ebuf + (size_t)b * CAP;
    if (t < 128) hp[t] = 0;
    __syncthreads();
    for (int i = t; i < cntb; i += 256) atomicAdd(&hp[eb[i] >> 25], 1);
    __syncthreads();
    int c0 = (t < 128) ? hp[t] : 0;
    for (int off = 1; off < 128; off <<= 1) {
        int a = (t >= off && t < 128) ? hp[t - off] : 0;
        __syncthreads();
        if (t < 128) hp[t] += a;
        __syncthreads();
    }
    if (t < 128) {
        int excl = hp[t] - c0;
        curp[t] = excl;
        lrp[t] = excl;
        if (t == 127) lrp[128] = hp[127];
        int d = (b << 7) + t;
        if (d < N) rp[d] = base + excl;
        if (d == N) rp[N] = base + excl;
    }
    __syncthreads();
    for (int i = t; i < cntb; i += 256) {
        unsigned pck = eb[i];
        int pos = atomicAdd(&curp[pck >> 25], 1);
        int sv = (int)(pck & 0x01FFFFFFu);
        lsrcs[pos] = sv;
        srcs[base + pos] = sv;
    }
    __syncthreads();

    // ---- gather into lA (phase B) ----
    const int lane = t & 63;
    const int w = t >> 6;
    const int q = lane >> 4, ql = lane & 15;
    const int qid = w * 4 + q;
    for (int nn = 0; nn < 8; ++nn) {
        const int loc = qid * 8 + nn;
        const int n = (b << 7) + loc;
        uint4 o = make_uint4(0u, 0u, 0u, 0u);
        if (n < N) o = gather_row(X4, n, ql, lrp, lsrcs, loc);
        *(uint4*)&lA[swz_base(loc, ql)] = o;
    }
    __syncthreads();   // gather done; uraw about to be overwritten by lW

    // ---- MLP (phase C) ----
    const int wr = (w >> 1) * 64;
    const int wc = (w & 1) * 64;
    f32x4 acc[4][4];
    mlp_core(lA, lW, WaT, ba, WbT, acc, t, lane, wr, wc);

    // epilogue: Y = relu(acc + bb), row-major bf16
    const int am = lane & 15;
    #pragma unroll
    for (int j = 0; j < 4; ++j) {
        int col = wc + j * 16 + am;
        float bias = bb[col];
        #pragma unroll
        for (int i = 0; i < 4; ++i) {
            int rowb = wr + i * 16 + (lane >> 4) * 4;
            #pragma unroll
            for (int r = 0; r < 4; ++r) {
                int row = (b << 7) + rowb + r;
                if (row < N) {
                    float v = acc[i][j][r] + bias;
                    v = v > 0.f ? v : 0.f;
                    Y[(size_t)row * 128 + col] = f2bf(v);
                }
            }
        }
    }
}

// ---------------- conv2: gather (global rp/srcs) + MLP + fused pool, one block per bucket ----------------
__global__ __launch_bounds__(256, 2)
void k_conv2(const int* __restrict__ rp, const int* __restrict__ srcs, int nbuck, int N,
             const uint4* __restrict__ H4,
             const unsigned short* __restrict__ WaT, const float* __restrict__ ba,
             const unsigned short* __restrict__ WbT, const float* __restrict__ bb,
             const int* __restrict__ batch, float* __restrict__ G) {
    __shared__ unsigned short lA[128 * 128];                       // 32 KB
    __shared__ __align__(16) unsigned char uraw[32 * 1024];        // {lrp,lsrcs} ∪ lW
    __shared__ int bs[128];
    int* lrp   = (int*)(uraw);             // [129]
    int* lsrcs = (int*)(uraw + 528);       // [CAP]
    unsigned short* lW = (unsigned short*)uraw;

    const int t = threadIdx.x;
    const int b = blockIdx.x;

    // ---- stage rp window + srcs slice ----
    if (t < 129) {
        int gd = (b << 7) + t;
        if (gd > N) gd = N;
        lrp[t] = rp[gd];
    }
    __syncthreads();
    const int base = lrp[0];
    const int cntb = lrp[128] - base;
    for (int i = t; i < cntb; i += 256) lsrcs[i] = srcs[base + i];
    if (t < 129) lrp[t] -= base;           // make relative
    __syncthreads();

    // ---- gather into lA ----
    const int lane = t & 63;
    const int w = t >> 6;
    const int q = lane >> 4, ql = lane & 15;
    const int qid = w * 4 + q;
    for (int nn = 0; nn < 8; ++nn) {
        const int loc = qid * 8 + nn;
        const int n = (b << 7) + loc;
        uint4 o = make_uint4(0u, 0u, 0u, 0u);
        if (n < N) o = gather_row(H4, n, ql, lrp, lsrcs, loc);
        *(uint4*)&lA[swz_base(loc, ql)] = o;
    }
    __syncthreads();

    // ---- MLP ----
    const int wr = (w >> 1) * 64;
    const int wc = (w & 1) * 64;
    f32x4 acc[4][4];
    mlp_core(lA, lW, WaT, ba, WbT, acc, t, lane, wr, wc);

    // ---- pool epilogue: R = relu(acc+bb) -> lA, segmented pool into G ----
    __syncthreads();   // mm2 lA/lW reads complete
    const int am = lane & 15;
    #pragma unroll
    for (int j = 0; j < 4; ++j) {
        int col = wc + j * 16 + am;
        float bias = bb[col];
        #pragma unroll
        for (int i = 0; i < 4; ++i) {
            int rowb = wr + i * 16 + (lane >> 4) * 4;
            #pragma unroll
            for (int r = 0; r < 4; ++r) {
                float v = acc[i][j][r] + bias;
                v = v > 0.f ? v : 0.f;
                int row = rowb + r;
                lA[swz_base(row, col >> 3) + (col & 7)] = f2bf(v);
            }
        }
    }
    if (t < 128) bs[t] = ((b << 7) + t < N) ? batch[(b << 7) + t] : -1;
    __syncthreads();
    const int col = t & 127;
    const int half = t >> 7;
    const int rbeg = half * 64, rend = rbeg + 64;
    float pacc = 0.f;
    int cur = bs[rbeg];
    for (int row = rbeg; row < rend; ++row) {
        int bg = bs[row];
        if (bg != cur) {
            if (cur >= 0) atomicAdd(&G[(size_t)cur * 128 + col], pacc);
            pacc = 0.f;
            cur = bg;
        }
        unsigned short u = lA[swz_base(row, col >> 3) + (col & 7)];
        pacc += __uint_as_float((unsigned)u << 16);
    }
    if (cur >= 0) atomicAdd(&G[(size_t)cur * 128 + col], pacc);
}

// ---------------- head ----------------
__global__ void k_head(const float* __restrict__ G,
                       const float* __restrict__ Wl1, const float* __restrict__ bl1,
                       const float* __restrict__ Wl2, const float* __restrict__ bl2,
                       int C, float* __restrict__ out) {
    __shared__ float sg[128];
    __shared__ float sh[128];
    __shared__ float sl[16];
    int row = blockIdx.x;
    int t = threadIdx.x;
    sg[t] = G[(size_t)row * 128 + t];
    __syncthreads();
    float a = bl1[t];
    for (int k = 0; k < 128; ++k) a += sg[k] * Wl1[k * 128 + t];
    sh[t] = a > 0.f ? a : 0.f;
    __syncthreads();
    if (t < C) {
        float l = bl2[t];
        for (int k = 0; k < 128; ++k) l += sh[k] * Wl2[k * C + t];
        sl[t] = l;
    }
    __syncthreads();
    if (t < C) {
        float m = -1e30f;
        for (int j = 0; j < C; ++j) m = fmaxf(m, sl[j]);
        float s = 0.f;
        for (int j = 0; j < C; ++j) s += __expf(sl[j] - m);
        out[(size_t)row * C + t] = sl[t] - m - __logf(s);
    }
}

extern "C" void kernel_launch(void* const* d_in, const int* in_sizes, int n_in,
                              void* d_out, int out_size, void* d_ws, size_t ws_size,
                              hipStream_t stream) {
    const float* x    = (const float*)d_in[0];
    const int*   ei   = (const int*)d_in[1];     // [2][E]
    const int*   batch= (const int*)d_in[2];
    const float* W1a  = (const float*)d_in[3];
    const float* b1a  = (const float*)d_in[4];
    const float* W1b  = (const float*)d_in[5];
    const float* b1b  = (const float*)d_in[6];
    const float* W2a  = (const float*)d_in[7];
    const float* b2a  = (const float*)d_in[8];
    const float* W2b  = (const float*)d_in[9];
    const float* b2b  = (const float*)d_in[10];
    const float* Wl1  = (const float*)d_in[11];
    const float* bl1  = (const float*)d_in[12];
    const float* Wl2  = (const float*)d_in[13];
    const float* bl2  = (const float*)d_in[14];
    float* out = (float*)d_out;

    const int N = in_sizes[2];
    const int E = in_sizes[1] / 2;
    const int C = in_sizes[13] / 128;

    const int nbuck = (N >> 7) + 1;
    const int epb = (E + SBLK - 1) / SBLK;

    char* p = (char*)d_ws;
    auto alloc = [&](size_t bytes) {
        char* r = p;
        p += (bytes + 255) & ~(size_t)255;
        return r;
    };
    unsigned* xb   = (unsigned*)alloc((size_t)N * 64 * 4);     // x bf16, row-major
    unsigned* hB   = (unsigned*)alloc((size_t)N * 64 * 4);     // conv1 out (bf16)
    float* g       = (float*)alloc((size_t)NUM_GRAPHS * 128 * 4);
    int* rp        = (int*)alloc((size_t)(N + 1) * 4);
    int* srcs      = (int*)alloc((size_t)E * 4);
    unsigned* ebuf = (unsigned*)alloc((size_t)nbuck * CAP * 4);
    int* gcur      = (int*)alloc((size_t)1024 * 4);
    unsigned short* wt = (unsigned short*)alloc((size_t)4 * 16384 * 2);
    (void)ws_size; (void)n_in; (void)out_size;

    hipMemsetAsync(gcur, 0, (size_t)nbuck * 4, stream);

    // CSR pass 1 (+ x->bf16, zero G, weight prep)
    k_sort<<<SBLK + 2048 + 64 + 256, 256, 0, stream>>>(
        ei, ei + E, E, epb, nbuck, gcur, ebuf, x, N, xb, g,
        W1a, W1b, W2a, W2b, wt);

    // conv1: CSR fine-sort + gather + MLP (one kernel)
    k_conv1<<<nbuck, 256, 0, stream>>>(ebuf, gcur, nbuck, N, rp, srcs,
                                       (const uint4*)xb, wt, b1a, wt + 16384, b1b,
                                       (unsigned short*)hB);
    // conv2: gather + MLP + pool (one kernel)
    k_conv2<<<nbuck, 256, 0, stream>>>(rp, srcs, nbuck, N,
                                       (const uint4*)hB, wt + 2 * 16384, b2a,
                                       wt + 3 * 16384, b2b, batch, g);
    // head
    k_head<<<NUM_GRAPHS, 128, 0, stream>>>(g, Wl1, bl1, Wl2, bl2, C, out);
}